// Round 12
// baseline (500.128 us; speedup 1.0000x reference)
//
#include <hip/hip_runtime.h>
#include <hip/hip_bf16.h>

// Problem: B=32, T=256, I=128, H=128, C=100. All fp32.
// out = (h_T + attn_c_final) @ w_fc.T + b_fc; only the LAST step's attention
// matters (scan carry overwrites attn_c each step).

#define Bsz 32
#define Tsz 256
#define Isz 128
#define Hsz 128
#define Csz 100
#define G4H 512   // 4*H

typedef short v8s __attribute__((ext_vector_type(8)));   // 8 bf16 = 4 VGPRs
typedef float v4fa __attribute__((ext_vector_type(4)));  // MFMA acc

// ---------------- device helpers ----------------
__device__ __forceinline__ float2 pk_fma(float2 a, float2 b, float2 c) {
    float2 d;
    asm("v_pk_fma_f32 %0, %1, %2, %3" : "=v"(d) : "v"(a), "v"(b), "v"(c));
    return d;
}
__device__ __forceinline__ float quad_rsum(float x) {
    int t = __builtin_amdgcn_update_dpp(0, __float_as_int(x), 0xB1, 0xF, 0xF, true); // xor 1
    x += __int_as_float(t);
    t = __builtin_amdgcn_update_dpp(0, __float_as_int(x), 0x4E, 0xF, 0xF, true);     // xor 2
    x += __int_as_float(t);
    return x;
}
__device__ __forceinline__ float pair_rsum(float x) {
    int t = __builtin_amdgcn_update_dpp(0, __float_as_int(x), 0xB1, 0xF, 0xF, true); // xor 1
    return x + __int_as_float(t);
}
__device__ __forceinline__ float rcpf(float x) { return __builtin_amdgcn_rcpf(x); }
__device__ __forceinline__ float sigm_n(float x) { return rcpf(1.0f + __expf(-x)); }
__device__ __forceinline__ float tanh_n(float x) {
    float ax = fabsf(x);
    float e = __expf(-2.0f * ax);
    float t = (1.0f - e) * rcpf(1.0f + e);
    return copysignf(t, x);
}
__device__ __forceinline__ float tanh_s(float x) { return tanh_n(x); }
__device__ __forceinline__ short bf16_bits(float x) {
    __hip_bfloat16 h = __float2bfloat16(x);
    return *reinterpret_cast<short*>(&h);
}
__device__ __forceinline__ float bf16_val(float x) {
    return __bfloat162float(__float2bfloat16(x));
}

// ---------------- kernel 0: weight prep ----------------
// whh_pk: packed for the 256-thread lstm:
//   float f-index = ((kk2*4 + gi) * 256 + t) * 2 + j,  t=(d<<1)|q
//   source: w_hh[(gi*128 + d)*128 + q*64 + kk2*2 + j]
// bias = b_ih + b_hh; attn_c zeroed.
// W2ih[n][k'] (512 x 384 bf16): [w_hi | w_lo | w_hi]; W2v likewise for w1 bottom.
__global__ __launch_bounds__(256) void prep_kernel(
    const float* __restrict__ w_ih, const float* __restrict__ b_ih,
    const float* __restrict__ w_hh, const float* __restrict__ b_hh,
    const float* __restrict__ w1,
    __hip_bfloat16* __restrict__ W2ih, __hip_bfloat16* __restrict__ W2v,
    float* __restrict__ whh_pk, float* __restrict__ bias,
    float* __restrict__ attn_c) {
    int idx = blockIdx.x * blockDim.x + threadIdx.x;   // 0..65535
    if (idx < G4H * Isz) {
        int n = idx >> 7;
        int k = idx & 127;
        float x = w_ih[idx];
        __hip_bfloat16 hi = __float2bfloat16(x);
        __hip_bfloat16 lo = __float2bfloat16(x - __bfloat162float(hi));
        W2ih[(size_t)n * 384 + k] = hi;
        W2ih[(size_t)n * 384 + 128 + k] = lo;
        W2ih[(size_t)n * 384 + 256 + k] = hi;

        // lstm packing (256-thread layout)
        int j   = idx & 1;
        int t   = (idx >> 1) & 255;
        int gi  = (idx >> 9) & 3;
        int kk2 = idx >> 11;           // 0..31
        int d   = t >> 1, q = t & 1;
        whh_pk[idx] = w_hh[(size_t)((gi << 7) + d) * 128 + (q << 6) + (kk2 << 1) + j];
    }
    if (idx < Hsz * Hsz) {
        int n = idx >> 7;
        int k = idx & 127;
        float x = w1[(size_t)(128 + k) * Hsz + n];
        __hip_bfloat16 hi = __float2bfloat16(x);
        __hip_bfloat16 lo = __float2bfloat16(x - __bfloat162float(hi));
        W2v[(size_t)n * 384 + k] = hi;
        W2v[(size_t)n * 384 + 128 + k] = lo;
        W2v[(size_t)n * 384 + 256 + k] = hi;
    }
    if (idx < G4H) bias[idx] = b_ih[idx] + b_hh[idx];
    if (idx < Bsz * Hsz) attn_c[idx] = 0.0f;
}

// ---------------- gemm_mfma_f32a: C[M,N] = split(A_fp32) @ split(W)^T (+bias) ----
__global__ __launch_bounds__(256) void gemm_mfma_f32a(
    const float* __restrict__ A, const __hip_bfloat16* __restrict__ W2,
    const float* __restrict__ bias, float* __restrict__ C, int M, int N) {
    const int tid = threadIdx.x;
    const int w = tid >> 6, lane = tid & 63;
    const int m0 = blockIdx.y * 64 + (w & 1) * 32;
    const int n0 = blockIdx.x * 64 + (w >> 1) * 32;
    const int r = lane & 15, quad = lane >> 4;

    v8s Ahi[2][4], Alo[2][4];
    #pragma unroll
    for (int i = 0; i < 2; ++i)
        #pragma unroll
        for (int cb = 0; cb < 4; ++cb) {
            const float* src = A + (size_t)(m0 + 16 * i + r) * Isz + cb * 32 + quad * 8;
            float4 f0 = *(const float4*)src;
            float4 f1 = *(const float4*)(src + 4);
            float f[8] = {f0.x, f0.y, f0.z, f0.w, f1.x, f1.y, f1.z, f1.w};
            v8s hi, lo;
            #pragma unroll
            for (int e = 0; e < 8; ++e) {
                float hv = bf16_val(f[e]);
                hi[e] = bf16_bits(f[e]);
                lo[e] = bf16_bits(f[e] - hv);
            }
            Ahi[i][cb] = hi;
            Alo[i][cb] = lo;
        }

    v4fa acc[2][2] = {};
    const short* Wb = (const short*)W2;
    #pragma unroll
    for (int ks = 0; ks < 12; ++ks) {
        int cb = ks & 3;
        v8s a0 = (ks >= 8) ? Alo[0][cb] : Ahi[0][cb];
        v8s a1 = (ks >= 8) ? Alo[1][cb] : Ahi[1][cb];
        int kb = ks * 32 + quad * 8;
        v8s b0 = *(const v8s*)(Wb + (size_t)(n0 + r) * 384 + kb);
        v8s b1 = *(const v8s*)(Wb + (size_t)(n0 + 16 + r) * 384 + kb);
        acc[0][0] = __builtin_amdgcn_mfma_f32_16x16x32_bf16(a0, b0, acc[0][0], 0, 0, 0);
        acc[0][1] = __builtin_amdgcn_mfma_f32_16x16x32_bf16(a0, b1, acc[0][1], 0, 0, 0);
        acc[1][0] = __builtin_amdgcn_mfma_f32_16x16x32_bf16(a1, b0, acc[1][0], 0, 0, 0);
        acc[1][1] = __builtin_amdgcn_mfma_f32_16x16x32_bf16(a1, b1, acc[1][1], 0, 0, 0);
    }
    // C/D layout: col = lane&15, row = quad*4 + reg  [verified m89/m91]
    #pragma unroll
    for (int i = 0; i < 2; ++i)
        #pragma unroll
        for (int j = 0; j < 2; ++j) {
            int cn = n0 + 16 * j + r;
            float bb = bias ? bias[cn] : 0.0f;
            #pragma unroll
            for (int rr = 0; rr < 4; ++rr) {
                int row = m0 + 16 * i + quad * 4 + rr;
                C[(size_t)row * N + cn] = acc[i][j][rr] + bb;
            }
        }
}

// ---------------- kernel 2: sequential LSTM, 256 threads (4 waves) ----------------
// Thread (d = tid>>1, q = tid&1) computes all 4 gates of dim d over k-slice
// [64q, 64q+64). Weights in 256 VGPRs; 1 wave/SIMD; single DPP-xor1 reduce;
// one 4-wave barrier per step (half the participants of the 8-wave variant).
__global__ __launch_bounds__(256, 1) void lstm_seq(
    const float* __restrict__ G, const float* __restrict__ whh_pk,
    float* __restrict__ H_all) {
    const int b = blockIdx.x;
    const int tid = threadIdx.x;
    const int d = tid >> 1;
    const int q = tid & 1;

    __shared__ float h_s[2][Hsz];

    // one-time coalesced weight load: w2v[gi][kk2] covers k = q*64 + kk2*2 {+0,+1}
    float2 w2v[4][32];
    {
        const float2* wp = (const float2*)whh_pk;
        #pragma unroll
        for (int kk2 = 0; kk2 < 32; ++kk2)
            #pragma unroll
            for (int gi = 0; gi < 4; ++gi)
                w2v[gi][kk2] = wp[(kk2 * 4 + gi) * 256 + tid];
    }

    if (tid < 2 * Hsz) ((float*)h_s)[tid] = 0.0f;
    float c = 0.0f;
    __syncthreads();

    // G seeds: lane q owns gates {q, q+2}
    const float* Gq0 = G + (size_t)b * Tsz * G4H + q * 128 + d;        // gate q
    const float* Gq2 = Gq0 + 256;                                      // gate q+2
    float* Hst = H_all + (size_t)b * Tsz * Hsz + d;   // q==0 lanes store

    float g0v = Gq0[0], g2v = Gq2[0];
    int cur = 0;
    for (int t = 0; t < Tsz; ++t) {
        const int tn = (t < Tsz - 1) ? t + 1 : t;
        float ng0 = Gq0[(size_t)tn * G4H];   // prefetch, independent of h
        float ng2 = Gq2[(size_t)tn * G4H];

        // acc[gi]: gate gi partial over this lane's 64-k slice (2 chains each)
        float2 accA[4], accB[4];
        #pragma unroll
        for (int gi = 0; gi < 4; ++gi) {
            accA[gi] = make_float2(0.f, 0.f);
            accB[gi] = make_float2(0.f, 0.f);
        }
        // seed: lane q adds G of gates q (into accA[q]) and q+2 (accA[q+2])
        accA[q].x = g0v;
        accA[q + 2].x = g2v;

        const float4* hb4 = (const float4*)&h_s[cur][q * 64];
        #pragma unroll
        for (int kk4 = 0; kk4 < 16; ++kk4) {
            float4 h4 = hb4[kk4];
            float2 hA = make_float2(h4.x, h4.y);
            float2 hB = make_float2(h4.z, h4.w);
            accA[0] = pk_fma(hA, w2v[0][2 * kk4], accA[0]);
            accA[1] = pk_fma(hA, w2v[1][2 * kk4], accA[1]);
            accA[2] = pk_fma(hA, w2v[2][2 * kk4], accA[2]);
            accA[3] = pk_fma(hA, w2v[3][2 * kk4], accA[3]);
            accB[0] = pk_fma(hB, w2v[0][2 * kk4 + 1], accB[0]);
            accB[1] = pk_fma(hB, w2v[1][2 * kk4 + 1], accB[1]);
            accB[2] = pk_fma(hB, w2v[2][2 * kk4 + 1], accB[2]);
            accB[3] = pk_fma(hB, w2v[3][2 * kk4 + 1], accB[3]);
        }
        // combine the two k-halves across the lane pair (single DPP hop)
        float a0 = pair_rsum(accA[0].x + accA[0].y + accB[0].x + accB[0].y);
        float a1 = pair_rsum(accA[1].x + accA[1].y + accB[1].x + accB[1].y);
        float a2 = pair_rsum(accA[2].x + accA[2].y + accB[2].x + accB[2].y);
        float a3 = pair_rsum(accA[3].x + accA[3].y + accB[3].x + accB[3].y);

        float iv = sigm_n(a0);
        float fv = sigm_n(a1);
        float gv = tanh_n(a2);
        float ov = sigm_n(a3);
        c = fv * c + iv * gv;
        float h = ov * tanh_n(c);

        if (q == 0) {
            h_s[cur ^ 1][d] = h;
            Hst[(size_t)t * Hsz] = h;
        }
        g0v = ng0;
        g2v = ng2;
        __syncthreads();
        cur ^= 1;
    }
}

// ---------------- kernel 3a: scores + partial attn_c, grid (4 jt, 32 b) ----------------
__global__ __launch_bounds__(256) void scores_part(
    const float* __restrict__ H_all, const float* __restrict__ KV,
    const float* __restrict__ w1, const float* __restrict__ w2,
    float* __restrict__ attn_c) {
    const int b = blockIdx.y, jt = blockIdx.x;
    const int tid = threadIdx.x;
    __shared__ float hT[Hsz];
    __shared__ float q_s[Hsz];
    __shared__ float w2s[Hsz];
    __shared__ float s_s[64];
    __shared__ float part[2][Hsz];

    const float* Hb = H_all + (size_t)b * Tsz * Hsz;
    const float* KVb = KV + (size_t)b * Tsz * Hsz;

    if (tid < Hsz) {
        hT[tid] = Hb[255 * Hsz + tid];
        w2s[tid] = w2[tid];
    }
    __syncthreads();
    if (tid < Hsz) {
        float acc = 0.f;
        #pragma unroll 8
        for (int k = 0; k < Hsz; ++k) acc = fmaf(hT[k], w1[k * Hsz + tid], acc);
        q_s[tid] = acc;
    }
    __syncthreads();

    const int jl = tid >> 2, ql = tid & 3;
    const int j = jt * 64 + jl;
    float p = 0.f;
    if (j < 255) {
        const float* kv = KVb + (size_t)j * Hsz + ql * 32;
        const float* qs = q_s + ql * 32;
        const float* wv = w2s + ql * 32;
        #pragma unroll 8
        for (int k = 0; k < 32; ++k)
            p = fmaf(tanh_s(qs[k] + kv[k]), wv[k], p);
    }
    p = quad_rsum(p);
    if (ql == 0) s_s[jl] = (j < 255) ? p : 0.0f;
    __syncthreads();

    {
        const int dd = tid & 127, half = tid >> 7;
        float acc = 0.f;
        #pragma unroll 4
        for (int u = 0; u < 32; ++u) {
            int lj = half * 32 + u;
            int jj = jt * 64 + lj;
            if (jj < 255) acc = fmaf(s_s[lj], Hb[(size_t)jj * Hsz + dd], acc);
        }
        part[half][dd] = acc;
    }
    __syncthreads();
    if (tid < Hsz) atomicAdd(&attn_c[b * Hsz + tid], part[0][tid] + part[1][tid]);
}

// ---------------- kernel 3b: final FC ----------------
__global__ __launch_bounds__(256) void fc_out(
    const float* __restrict__ H_all, const float* __restrict__ attn_c,
    const float* __restrict__ w_fc, const float* __restrict__ b_fc,
    float* __restrict__ out) {
    const int b = blockIdx.x, tid = threadIdx.x;
    __shared__ float r_s[Hsz];
    if (tid < Hsz)
        r_s[tid] = H_all[(size_t)b * Tsz * Hsz + 255 * Hsz + tid] + attn_c[b * Hsz + tid];
    __syncthreads();
    const int o = tid >> 1, half = tid & 1;
    float acc = 0.f;
    if (o < Csz) {
        const float* wr = w_fc + (size_t)o * Hsz + half * 64;
        const float* rr = r_s + half * 64;
        #pragma unroll 8
        for (int k = 0; k < 64; ++k) acc = fmaf(rr[k], wr[k], acc);
    }
    acc += __shfl_xor(acc, 1);
    if (half == 0 && o < Csz) out[b * Csz + o] = acc + b_fc[o];
}

// ---------------- launch ----------------
extern "C" void kernel_launch(void* const* d_in, const int* in_sizes, int n_in,
                              void* d_out, int out_size, void* d_ws, size_t ws_size,
                              hipStream_t stream) {
    const float* x    = (const float*)d_in[0];
    const float* w_ih = (const float*)d_in[1];
    const float* b_ih = (const float*)d_in[2];
    const float* w_hh = (const float*)d_in[3];
    const float* b_hh = (const float*)d_in[4];
    const float* w1   = (const float*)d_in[5];
    const float* w2   = (const float*)d_in[6];
    const float* w_fc = (const float*)d_in[7];
    const float* b_fc = (const float*)d_in[8];

    float* ws = (float*)d_ws;
    float* whh_pk = ws;                               // 65536 f
    float* bias   = whh_pk + 65536;                   // 512 f
    float* attn_c = bias + 512;                       // 4096 f
    __hip_bfloat16* W2ih = (__hip_bfloat16*)(attn_c + 4096);         // 98304 f
    __hip_bfloat16* W2v  = (__hip_bfloat16*)(attn_c + 4096 + 98304); // 24576 f
    float* G      = attn_c + 4096 + 98304 + 24576;    // 8192*512 = 4194304 f
    float* H_all  = G + 4194304;                      // 1048576 f
    float* KV     = H_all + 1048576;                  // 1048576 f

    prep_kernel<<<256, 256, 0, stream>>>(w_ih, b_ih, w_hh, b_hh, w1,
                                         W2ih, W2v, whh_pk, bias, attn_c);

    dim3 gG(G4H / 64, (Bsz * Tsz) / 64);              // (8, 128)
    gemm_mfma_f32a<<<gG, 256, 0, stream>>>(x, W2ih, bias, G, Bsz * Tsz, G4H);

    lstm_seq<<<Bsz, 256, 0, stream>>>(G, whh_pk, H_all);

    dim3 gK(Hsz / 64, (Bsz * Tsz) / 64);              // (2, 128)
    gemm_mfma_f32a<<<gK, 256, 0, stream>>>(H_all, W2v, nullptr, KV, Bsz * Tsz, Hsz);

    dim3 gS(4, Bsz);                                  // (4 jt, 32 b)
    scores_part<<<gS, 256, 0, stream>>>(H_all, KV, w1, w2, attn_c);

    fc_out<<<Bsz, 256, 0, stream>>>(H_all, attn_c, w_fc, b_fc, (float*)d_out);
}

// Round 13
// 443.018 us; speedup vs baseline: 1.1289x; 1.1289x over previous
//
#include <hip/hip_runtime.h>
#include <hip/hip_bf16.h>

// Problem: B=32, T=256, I=128, H=128, C=100. All fp32.
// out = (h_T + attn_c_final) @ w_fc.T + b_fc; only the LAST step's attention
// matters (scan carry overwrites attn_c each step).

#define Bsz 32
#define Tsz 256
#define Isz 128
#define Hsz 128
#define Csz 100
#define G4H 512   // 4*H

typedef short v8s __attribute__((ext_vector_type(8)));   // 8 bf16 = 4 VGPRs
typedef float v4fa __attribute__((ext_vector_type(4)));  // MFMA acc

// ---------------- device helpers ----------------
__device__ __forceinline__ float2 pk_fma(float2 a, float2 b, float2 c) {
    float2 d;
    asm("v_pk_fma_f32 %0, %1, %2, %3" : "=v"(d) : "v"(a), "v"(b), "v"(c));
    return d;
}
__device__ __forceinline__ float quad_rsum(float x) {
    int t = __builtin_amdgcn_update_dpp(0, __float_as_int(x), 0xB1, 0xF, 0xF, true); // xor 1
    x += __int_as_float(t);
    t = __builtin_amdgcn_update_dpp(0, __float_as_int(x), 0x4E, 0xF, 0xF, true);     // xor 2
    x += __int_as_float(t);
    return x;
}
// sum across 8 consecutive lanes: xor1, xor2, then ROW_HALF_MIRROR (0x141)
__device__ __forceinline__ float oct_rsum(float x) {
    int t = __builtin_amdgcn_update_dpp(0, __float_as_int(x), 0xB1, 0xF, 0xF, true);
    x += __int_as_float(t);
    t = __builtin_amdgcn_update_dpp(0, __float_as_int(x), 0x4E, 0xF, 0xF, true);
    x += __int_as_float(t);
    t = __builtin_amdgcn_update_dpp(0, __float_as_int(x), 0x141, 0xF, 0xF, true);    // half-mirror
    x += __int_as_float(t);
    return x;
}
__device__ __forceinline__ float rcpf(float x) { return __builtin_amdgcn_rcpf(x); }
__device__ __forceinline__ float sigm_n(float x) { return rcpf(1.0f + __expf(-x)); }
__device__ __forceinline__ float tanh_n(float x) {
    float ax = fabsf(x);
    float e = __expf(-2.0f * ax);
    float t = (1.0f - e) * rcpf(1.0f + e);
    return copysignf(t, x);
}
__device__ __forceinline__ float tanh_s(float x) { return tanh_n(x); }
__device__ __forceinline__ short bf16_bits(float x) {
    __hip_bfloat16 h = __float2bfloat16(x);
    return *reinterpret_cast<short*>(&h);
}
__device__ __forceinline__ float bf16_val(float x) {
    return __bfloat162float(__float2bfloat16(x));
}

// ---------------- kernel 0: weight prep ----------------
// whh_pk: packed for the 1024-thread lstm:
//   float idx = (c*1024 + t)*4 + j,  t = d*8 + q (== tid), c = kc*4 + gi
//   source: w_hh[(gi*128 + d)*128 + q*16 + kc*4 + j]
// bias = b_ih + b_hh; attn_c zeroed.
// W2ih[n][k'] (512 x 384 bf16): [w_hi | w_lo | w_hi]; W2v likewise for w1 bottom.
__global__ __launch_bounds__(256) void prep_kernel(
    const float* __restrict__ w_ih, const float* __restrict__ b_ih,
    const float* __restrict__ w_hh, const float* __restrict__ b_hh,
    const float* __restrict__ w1,
    __hip_bfloat16* __restrict__ W2ih, __hip_bfloat16* __restrict__ W2v,
    float* __restrict__ whh_pk, float* __restrict__ bias,
    float* __restrict__ attn_c) {
    int idx = blockIdx.x * blockDim.x + threadIdx.x;   // 0..65535
    if (idx < G4H * Isz) {
        int n = idx >> 7;
        int k = idx & 127;
        float x = w_ih[idx];
        __hip_bfloat16 hi = __float2bfloat16(x);
        __hip_bfloat16 lo = __float2bfloat16(x - __bfloat162float(hi));
        W2ih[(size_t)n * 384 + k] = hi;
        W2ih[(size_t)n * 384 + 128 + k] = lo;
        W2ih[(size_t)n * 384 + 256 + k] = hi;

        // lstm packing (1024-thread layout)
        int j  = idx & 3;
        int t  = (idx >> 2) & 1023;
        int c  = idx >> 12;            // 0..15
        int d  = t >> 3, q = t & 7;
        int gi = c & 3, kc = c >> 2;
        whh_pk[idx] = w_hh[(size_t)((gi << 7) + d) * 128 + (q << 4) + (kc << 2) + j];
    }
    if (idx < Hsz * Hsz) {
        int n = idx >> 7;
        int k = idx & 127;
        float x = w1[(size_t)(128 + k) * Hsz + n];
        __hip_bfloat16 hi = __float2bfloat16(x);
        __hip_bfloat16 lo = __float2bfloat16(x - __bfloat162float(hi));
        W2v[(size_t)n * 384 + k] = hi;
        W2v[(size_t)n * 384 + 128 + k] = lo;
        W2v[(size_t)n * 384 + 256 + k] = hi;
    }
    if (idx < G4H) bias[idx] = b_ih[idx] + b_hh[idx];
    if (idx < Bsz * Hsz) attn_c[idx] = 0.0f;
}

// ---------------- gemm_mfma_f32a: C[M,N] = split(A_fp32) @ split(W)^T (+bias) ----
__global__ __launch_bounds__(256) void gemm_mfma_f32a(
    const float* __restrict__ A, const __hip_bfloat16* __restrict__ W2,
    const float* __restrict__ bias, float* __restrict__ C, int M, int N) {
    const int tid = threadIdx.x;
    const int w = tid >> 6, lane = tid & 63;
    const int m0 = blockIdx.y * 64 + (w & 1) * 32;
    const int n0 = blockIdx.x * 64 + (w >> 1) * 32;
    const int r = lane & 15, quad = lane >> 4;

    v8s Ahi[2][4], Alo[2][4];
    #pragma unroll
    for (int i = 0; i < 2; ++i)
        #pragma unroll
        for (int cb = 0; cb < 4; ++cb) {
            const float* src = A + (size_t)(m0 + 16 * i + r) * Isz + cb * 32 + quad * 8;
            float4 f0 = *(const float4*)src;
            float4 f1 = *(const float4*)(src + 4);
            float f[8] = {f0.x, f0.y, f0.z, f0.w, f1.x, f1.y, f1.z, f1.w};
            v8s hi, lo;
            #pragma unroll
            for (int e = 0; e < 8; ++e) {
                float hv = bf16_val(f[e]);
                hi[e] = bf16_bits(f[e]);
                lo[e] = bf16_bits(f[e] - hv);
            }
            Ahi[i][cb] = hi;
            Alo[i][cb] = lo;
        }

    v4fa acc[2][2] = {};
    const short* Wb = (const short*)W2;
    #pragma unroll
    for (int ks = 0; ks < 12; ++ks) {
        int cb = ks & 3;
        v8s a0 = (ks >= 8) ? Alo[0][cb] : Ahi[0][cb];
        v8s a1 = (ks >= 8) ? Alo[1][cb] : Ahi[1][cb];
        int kb = ks * 32 + quad * 8;
        v8s b0 = *(const v8s*)(Wb + (size_t)(n0 + r) * 384 + kb);
        v8s b1 = *(const v8s*)(Wb + (size_t)(n0 + 16 + r) * 384 + kb);
        acc[0][0] = __builtin_amdgcn_mfma_f32_16x16x32_bf16(a0, b0, acc[0][0], 0, 0, 0);
        acc[0][1] = __builtin_amdgcn_mfma_f32_16x16x32_bf16(a0, b1, acc[0][1], 0, 0, 0);
        acc[1][0] = __builtin_amdgcn_mfma_f32_16x16x32_bf16(a1, b0, acc[1][0], 0, 0, 0);
        acc[1][1] = __builtin_amdgcn_mfma_f32_16x16x32_bf16(a1, b1, acc[1][1], 0, 0, 0);
    }
    // C/D layout: col = lane&15, row = quad*4 + reg  [verified m89/m91]
    #pragma unroll
    for (int i = 0; i < 2; ++i)
        #pragma unroll
        for (int j = 0; j < 2; ++j) {
            int cn = n0 + 16 * j + r;
            float bb = bias ? bias[cn] : 0.0f;
            #pragma unroll
            for (int rr = 0; rr < 4; ++rr) {
                int row = m0 + 16 * i + quad * 4 + rr;
                C[(size_t)row * N + cn] = acc[i][j][rr] + bb;
            }
        }
}

// ---------------- kernel 2: sequential LSTM, 1024 threads, reg-resident weights ----
// Thread (d = tid>>3, q = tid&7): all 4 gates of dim d over k-slice
// [16q, 16q+16). Weights = 16 NAMED float4 vars (64 VGPRs) -> SROA-trivial,
// no array to spill (R3..R12 all silently spilled their weight arrays and were
// reload-bandwidth-bound at ~256 KB/CU/step). 3-DPP-hop oct reduction.
__global__ __launch_bounds__(1024, 4) void lstm_seq(
    const float* __restrict__ G, const float* __restrict__ whh_pk,
    float* __restrict__ H_all) {
    const int b = blockIdx.x;
    const int tid = threadIdx.x;
    const int d = tid >> 3;
    const int q = tid & 7;

    __shared__ float h_s[2][Hsz];

    // one-time coalesced weight load into 16 named float4s (chunk c = kc*4+gi)
    const float4* wp4 = (const float4*)whh_pk;
#define WL(c) float4 w##c = wp4[(c) * 1024 + tid];
    WL(0) WL(1) WL(2) WL(3) WL(4) WL(5) WL(6) WL(7)
    WL(8) WL(9) WL(10) WL(11) WL(12) WL(13) WL(14) WL(15)
#undef WL

    if (tid < 2 * Hsz) ((float*)h_s)[tid] = 0.0f;
    float c = 0.0f;
    __syncthreads();

    // lane q<4 seeds gate q with its G value
    const float* Gq = G + (size_t)b * Tsz * G4H + q * 128 + d;   // valid for q<4
    float* Hst = H_all + (size_t)b * Tsz * Hsz + d;              // q==0 lanes store

    float gval = (q < 4) ? Gq[0] : 0.0f;
    int cur = 0;
    for (int t = 0; t < Tsz; ++t) {
        const int tn = (t < Tsz - 1) ? t + 1 : t;
        float ngval = (q < 4) ? Gq[(size_t)tn * G4H] : 0.0f;   // prefetch

        float s0 = (q == 0) ? gval : 0.f;
        float s1 = (q == 1) ? gval : 0.f;
        float s2 = (q == 2) ? gval : 0.f;
        float s3 = (q == 3) ? gval : 0.f;
        float2 A0 = make_float2(s0, 0.f), B0 = make_float2(0.f, 0.f);
        float2 A1 = make_float2(s1, 0.f), B1 = make_float2(0.f, 0.f);
        float2 A2 = make_float2(s2, 0.f), B2 = make_float2(0.f, 0.f);
        float2 A3 = make_float2(s3, 0.f), B3 = make_float2(0.f, 0.f);

        const float4* hb4 = (const float4*)&h_s[cur][q * 16];
        float4 h0 = hb4[0], h1 = hb4[1], h2 = hb4[2], h3 = hb4[3];

#define KCBLK(h4, g0, g1, g2, g3) { \
        float2 hA = make_float2(h4.x, h4.y), hB = make_float2(h4.z, h4.w); \
        A0 = pk_fma(hA, make_float2(g0.x, g0.y), A0); \
        B0 = pk_fma(hB, make_float2(g0.z, g0.w), B0); \
        A1 = pk_fma(hA, make_float2(g1.x, g1.y), A1); \
        B1 = pk_fma(hB, make_float2(g1.z, g1.w), B1); \
        A2 = pk_fma(hA, make_float2(g2.x, g2.y), A2); \
        B2 = pk_fma(hB, make_float2(g2.z, g2.w), B2); \
        A3 = pk_fma(hA, make_float2(g3.x, g3.y), A3); \
        B3 = pk_fma(hB, make_float2(g3.z, g3.w), B3); }

        KCBLK(h0, w0, w1, w2, w3)
        KCBLK(h1, w4, w5, w6, w7)
        KCBLK(h2, w8, w9, w10, w11)
        KCBLK(h3, w12, w13, w14, w15)
#undef KCBLK

        float a0 = oct_rsum(A0.x + A0.y + B0.x + B0.y);
        float a1 = oct_rsum(A1.x + A1.y + B1.x + B1.y);
        float a2 = oct_rsum(A2.x + A2.y + B2.x + B2.y);
        float a3 = oct_rsum(A3.x + A3.y + B3.x + B3.y);

        float iv = sigm_n(a0);
        float fv = sigm_n(a1);
        float gv = tanh_n(a2);
        float ov = sigm_n(a3);
        c = fv * c + iv * gv;
        float h = ov * tanh_n(c);

        if (q == 0) {
            h_s[cur ^ 1][d] = h;
            Hst[(size_t)t * Hsz] = h;
        }
        gval = ngval;
        __syncthreads();
        cur ^= 1;
    }
}

// ---------------- kernel 3a: scores + partial attn_c, grid (4 jt, 32 b) ----------------
__global__ __launch_bounds__(256) void scores_part(
    const float* __restrict__ H_all, const float* __restrict__ KV,
    const float* __restrict__ w1, const float* __restrict__ w2,
    float* __restrict__ attn_c) {
    const int b = blockIdx.y, jt = blockIdx.x;
    const int tid = threadIdx.x;
    __shared__ float hT[Hsz];
    __shared__ float q_s[Hsz];
    __shared__ float w2s[Hsz];
    __shared__ float s_s[64];
    __shared__ float part[2][Hsz];

    const float* Hb = H_all + (size_t)b * Tsz * Hsz;
    const float* KVb = KV + (size_t)b * Tsz * Hsz;

    if (tid < Hsz) {
        hT[tid] = Hb[255 * Hsz + tid];
        w2s[tid] = w2[tid];
    }
    __syncthreads();
    if (tid < Hsz) {
        float acc = 0.f;
        #pragma unroll 8
        for (int k = 0; k < Hsz; ++k) acc = fmaf(hT[k], w1[k * Hsz + tid], acc);
        q_s[tid] = acc;
    }
    __syncthreads();

    const int jl = tid >> 2, ql = tid & 3;
    const int j = jt * 64 + jl;
    float p = 0.f;
    if (j < 255) {
        const float* kv = KVb + (size_t)j * Hsz + ql * 32;
        const float* qs = q_s + ql * 32;
        const float* wv = w2s + ql * 32;
        #pragma unroll 8
        for (int k = 0; k < 32; ++k)
            p = fmaf(tanh_s(qs[k] + kv[k]), wv[k], p);
    }
    p = quad_rsum(p);
    if (ql == 0) s_s[jl] = (j < 255) ? p : 0.0f;
    __syncthreads();

    {
        const int dd = tid & 127, half = tid >> 7;
        float acc = 0.f;
        #pragma unroll 4
        for (int u = 0; u < 32; ++u) {
            int lj = half * 32 + u;
            int jj = jt * 64 + lj;
            if (jj < 255) acc = fmaf(s_s[lj], Hb[(size_t)jj * Hsz + dd], acc);
        }
        part[half][dd] = acc;
    }
    __syncthreads();
    if (tid < Hsz) atomicAdd(&attn_c[b * Hsz + tid], part[0][tid] + part[1][tid]);
}

// ---------------- kernel 3b: final FC ----------------
__global__ __launch_bounds__(256) void fc_out(
    const float* __restrict__ H_all, const float* __restrict__ attn_c,
    const float* __restrict__ w_fc, const float* __restrict__ b_fc,
    float* __restrict__ out) {
    const int b = blockIdx.x, tid = threadIdx.x;
    __shared__ float r_s[Hsz];
    if (tid < Hsz)
        r_s[tid] = H_all[(size_t)b * Tsz * Hsz + 255 * Hsz + tid] + attn_c[b * Hsz + tid];
    __syncthreads();
    const int o = tid >> 1, half = tid & 1;
    float acc = 0.f;
    if (o < Csz) {
        const float* wr = w_fc + (size_t)o * Hsz + half * 64;
        const float* rr = r_s + half * 64;
        #pragma unroll 8
        for (int k = 0; k < 64; ++k) acc = fmaf(rr[k], wr[k], acc);
    }
    acc += __shfl_xor(acc, 1);
    if (half == 0 && o < Csz) out[b * Csz + o] = acc + b_fc[o];
}

// ---------------- launch ----------------
extern "C" void kernel_launch(void* const* d_in, const int* in_sizes, int n_in,
                              void* d_out, int out_size, void* d_ws, size_t ws_size,
                              hipStream_t stream) {
    const float* x    = (const float*)d_in[0];
    const float* w_ih = (const float*)d_in[1];
    const float* b_ih = (const float*)d_in[2];
    const float* w_hh = (const float*)d_in[3];
    const float* b_hh = (const float*)d_in[4];
    const float* w1   = (const float*)d_in[5];
    const float* w2   = (const float*)d_in[6];
    const float* w_fc = (const float*)d_in[7];
    const float* b_fc = (const float*)d_in[8];

    float* ws = (float*)d_ws;
    float* whh_pk = ws;                               // 65536 f
    float* bias   = whh_pk + 65536;                   // 512 f
    float* attn_c = bias + 512;                       // 4096 f
    __hip_bfloat16* W2ih = (__hip_bfloat16*)(attn_c + 4096);         // 98304 f
    __hip_bfloat16* W2v  = (__hip_bfloat16*)(attn_c + 4096 + 98304); // 24576 f
    float* G      = attn_c + 4096 + 98304 + 24576;    // 8192*512 = 4194304 f
    float* H_all  = G + 4194304;                      // 1048576 f
    float* KV     = H_all + 1048576;                  // 1048576 f

    prep_kernel<<<256, 256, 0, stream>>>(w_ih, b_ih, w_hh, b_hh, w1,
                                         W2ih, W2v, whh_pk, bias, attn_c);

    dim3 gG(G4H / 64, (Bsz * Tsz) / 64);              // (8, 128)
    gemm_mfma_f32a<<<gG, 256, 0, stream>>>(x, W2ih, bias, G, Bsz * Tsz, G4H);

    lstm_seq<<<Bsz, 1024, 0, stream>>>(G, whh_pk, H_all);

    dim3 gK(Hsz / 64, (Bsz * Tsz) / 64);              // (2, 128)
    gemm_mfma_f32a<<<gK, 256, 0, stream>>>(H_all, W2v, nullptr, KV, Bsz * Tsz, Hsz);

    dim3 gS(4, Bsz);                                  // (4 jt, 32 b)
    scores_part<<<gS, 256, 0, stream>>>(H_all, KV, w1, w2, attn_c);

    fc_out<<<Bsz, 256, 0, stream>>>(H_all, attn_c, w_fc, b_fc, (float*)d_out);
}

// Round 15
// 333.387 us; speedup vs baseline: 1.5001x; 1.3288x over previous
//
#include <hip/hip_runtime.h>
#include <hip/hip_bf16.h>

// Problem: B=32, T=256, I=128, H=128, C=100. All fp32.
// out = (h_T + attn_c_final) @ w_fc.T + b_fc; only the LAST step's attention
// matters (scan carry overwrites attn_c each step).

#define Bsz 32
#define Tsz 256
#define Isz 128
#define Hsz 128
#define Csz 100
#define G4H 512   // 4*H

typedef short v8s __attribute__((ext_vector_type(8)));   // 8 bf16 = 4 VGPRs
typedef float v4fa __attribute__((ext_vector_type(4)));  // MFMA acc

// ---------------- device helpers ----------------
__device__ __forceinline__ float2 pk_fma(float2 a, float2 b, float2 c) {
    float2 d;
    asm("v_pk_fma_f32 %0, %1, %2, %3" : "=v"(d) : "v"(a), "v"(b), "v"(c));
    return d;
}
__device__ __forceinline__ float quad_rsum(float x) {
    int t = __builtin_amdgcn_update_dpp(0, __float_as_int(x), 0xB1, 0xF, 0xF, true); // xor 1
    x += __int_as_float(t);
    t = __builtin_amdgcn_update_dpp(0, __float_as_int(x), 0x4E, 0xF, 0xF, true);     // xor 2
    x += __int_as_float(t);
    return x;
}
__device__ __forceinline__ float rcpf(float x) { return __builtin_amdgcn_rcpf(x); }
__device__ __forceinline__ float sigm_n(float x) { return rcpf(1.0f + __expf(-x)); }
__device__ __forceinline__ float tanh_n(float x) {
    float ax = fabsf(x);
    float e = __expf(-2.0f * ax);
    float t = (1.0f - e) * rcpf(1.0f + e);
    return copysignf(t, x);
}
__device__ __forceinline__ float tanh_s(float x) { return tanh_n(x); }
__device__ __forceinline__ short bf16_bits(float x) {
    __hip_bfloat16 h = __float2bfloat16(x);
    return *reinterpret_cast<short*>(&h);
}
__device__ __forceinline__ float bf16_val(float x) {
    return __bfloat162float(__float2bfloat16(x));
}

// ---------------- kernel 0: weight prep ----------------
// whh_pk: packed for the 512-thread lstm; dest idx bit fields:
//   [1:0]=j4, [3:2]=q, [10:4]=d, [12:11]=gi, [15:13]=kk4
//   source k = q*32 + kk4*4 + j4, source row j = gi*128 + d  (w_hh is (4H,H))
// bias = b_ih + b_hh; attn_c zeroed.
// W2ih[n][k'] (512 x 384 bf16): [w_hi | w_lo | w_hi]; W2v likewise for w1 bottom.
__global__ __launch_bounds__(256) void prep_kernel(
    const float* __restrict__ w_ih, const float* __restrict__ b_ih,
    const float* __restrict__ w_hh, const float* __restrict__ b_hh,
    const float* __restrict__ w1,
    __hip_bfloat16* __restrict__ W2ih, __hip_bfloat16* __restrict__ W2v,
    float* __restrict__ whh_pk, float* __restrict__ bias,
    float* __restrict__ attn_c) {
    int idx = blockIdx.x * blockDim.x + threadIdx.x;   // 0..65535
    if (idx < G4H * Isz) {
        int n = idx >> 7;
        int k = idx & 127;
        float x = w_ih[idx];
        __hip_bfloat16 hi = __float2bfloat16(x);
        __hip_bfloat16 lo = __float2bfloat16(x - __bfloat162float(hi));
        W2ih[(size_t)n * 384 + k] = hi;
        W2ih[(size_t)n * 384 + 128 + k] = lo;
        W2ih[(size_t)n * 384 + 256 + k] = hi;

        // lstm packing (512-thread layout, same as R3/R6/R9)
        int j4  = idx & 3;
        int q   = (idx >> 2) & 3;
        int d   = (idx >> 4) & 127;
        int gi  = (idx >> 11) & 3;
        int kk4 = (idx >> 13) & 7;
        whh_pk[idx] = w_hh[(size_t)((gi << 7) + d) * 128 + (q << 5) + (kk4 << 2) + j4];
    }
    if (idx < Hsz * Hsz) {
        int n = idx >> 7;
        int k = idx & 127;
        float x = w1[(size_t)(128 + k) * Hsz + n];
        __hip_bfloat16 hi = __float2bfloat16(x);
        __hip_bfloat16 lo = __float2bfloat16(x - __bfloat162float(hi));
        W2v[(size_t)n * 384 + k] = hi;
        W2v[(size_t)n * 384 + 128 + k] = lo;
        W2v[(size_t)n * 384 + 256 + k] = hi;
    }
    if (idx < G4H) bias[idx] = b_ih[idx] + b_hh[idx];
    if (idx < Bsz * Hsz) attn_c[idx] = 0.0f;
}

// ---------------- gemm_mfma_f32a: C[M,N] = split(A_fp32) @ split(W)^T (+bias) ----
__global__ __launch_bounds__(256) void gemm_mfma_f32a(
    const float* __restrict__ A, const __hip_bfloat16* __restrict__ W2,
    const float* __restrict__ bias, float* __restrict__ C, int M, int N) {
    const int tid = threadIdx.x;
    const int w = tid >> 6, lane = tid & 63;
    const int m0 = blockIdx.y * 64 + (w & 1) * 32;
    const int n0 = blockIdx.x * 64 + (w >> 1) * 32;
    const int r = lane & 15, quad = lane >> 4;

    v8s Ahi[2][4], Alo[2][4];
    #pragma unroll
    for (int i = 0; i < 2; ++i)
        #pragma unroll
        for (int cb = 0; cb < 4; ++cb) {
            const float* src = A + (size_t)(m0 + 16 * i + r) * Isz + cb * 32 + quad * 8;
            float4 f0 = *(const float4*)src;
            float4 f1 = *(const float4*)(src + 4);
            float f[8] = {f0.x, f0.y, f0.z, f0.w, f1.x, f1.y, f1.z, f1.w};
            v8s hi, lo;
            #pragma unroll
            for (int e = 0; e < 8; ++e) {
                float hv = bf16_val(f[e]);
                hi[e] = bf16_bits(f[e]);
                lo[e] = bf16_bits(f[e] - hv);
            }
            Ahi[i][cb] = hi;
            Alo[i][cb] = lo;
        }

    v4fa acc[2][2] = {};
    const short* Wb = (const short*)W2;
    #pragma unroll
    for (int ks = 0; ks < 12; ++ks) {
        int cb = ks & 3;
        v8s a0 = (ks >= 8) ? Alo[0][cb] : Ahi[0][cb];
        v8s a1 = (ks >= 8) ? Alo[1][cb] : Ahi[1][cb];
        int kb = ks * 32 + quad * 8;
        v8s b0 = *(const v8s*)(Wb + (size_t)(n0 + r) * 384 + kb);
        v8s b1 = *(const v8s*)(Wb + (size_t)(n0 + 16 + r) * 384 + kb);
        acc[0][0] = __builtin_amdgcn_mfma_f32_16x16x32_bf16(a0, b0, acc[0][0], 0, 0, 0);
        acc[0][1] = __builtin_amdgcn_mfma_f32_16x16x32_bf16(a0, b1, acc[0][1], 0, 0, 0);
        acc[1][0] = __builtin_amdgcn_mfma_f32_16x16x32_bf16(a1, b0, acc[1][0], 0, 0, 0);
        acc[1][1] = __builtin_amdgcn_mfma_f32_16x16x32_bf16(a1, b1, acc[1][1], 0, 0, 0);
    }
    // C/D layout: col = lane&15, row = quad*4 + reg  [verified m89/m91]
    #pragma unroll
    for (int i = 0; i < 2; ++i)
        #pragma unroll
        for (int j = 0; j < 2; ++j) {
            int cn = n0 + 16 * j + r;
            float bb = bias ? bias[cn] : 0.0f;
            #pragma unroll
            for (int rr = 0; rr < 4; ++rr) {
                int row = m0 + 16 * i + quad * 4 + rr;
                C[(size_t)row * N + cn] = acc[i][j][rr] + bb;
            }
        }
}

// ---------------- kernel 2: sequential LSTM, 512 thr, PINNED reg weights ----
// R3/R6 structure. KEY: the 32 weight float4s are pinned per-COMPONENT via
// opaque asm ("+v" on scalar floats — float4 aggregates are rejected by LLVM).
// The compiler cannot rematerialize them from memory, so ~128 VGPRs stay live
// across the loop. (R3-R13 all silently re-streamed 256 KB/CU/step of weights
// from L2 — VGPR_Count 56-148 always < declared weight footprint.)
#define HPAD(k) ((k) + 8 * ((k) >> 5))

__global__ __launch_bounds__(512, 2) void lstm_seq(
    const float* __restrict__ G, const float* __restrict__ whh_pk,
    float* __restrict__ H_all) {
    const int b = blockIdx.x;
    const int tid = threadIdx.x;
    const int d = tid >> 2;
    const int q = tid & 3;

    __shared__ float h_s[2][160];

    // one-time coalesced weight load into 32 NAMED float4s, pinned per scalar.
    // chunk c = kk4*4 + gi holds gate gi, k-offsets {2kk4, 2kk4+1} (pairs).
    const float4* wp = (const float4*)whh_pk;
#define WLOAD(c) float4 W##c = wp[((c) * 128 + d) * 4 + q]; \
                 asm volatile("" : "+v"(W##c.x), "+v"(W##c.y), "+v"(W##c.z), "+v"(W##c.w));
    WLOAD(0)  WLOAD(1)  WLOAD(2)  WLOAD(3)
    WLOAD(4)  WLOAD(5)  WLOAD(6)  WLOAD(7)
    WLOAD(8)  WLOAD(9)  WLOAD(10) WLOAD(11)
    WLOAD(12) WLOAD(13) WLOAD(14) WLOAD(15)
    WLOAD(16) WLOAD(17) WLOAD(18) WLOAD(19)
    WLOAD(20) WLOAD(21) WLOAD(22) WLOAD(23)
    WLOAD(24) WLOAD(25) WLOAD(26) WLOAD(27)
    WLOAD(28) WLOAD(29) WLOAD(30) WLOAD(31)
#undef WLOAD

    if (tid < 320) ((float*)h_s)[tid] = 0.0f;
    float c = 0.0f;
    __syncthreads();

    const float* Gq = G + (size_t)b * Tsz * G4H + q * 128 + d;
    float* Hst = H_all + (size_t)b * Tsz * Hsz + d;   // q==0 lanes store

    float gval = Gq[0];
    int cur = 0;
    for (int t = 0; t < Tsz; ++t) {
        const int tn = (t < Tsz - 1) ? t + 1 : t;
        float ngval = Gq[(size_t)tn * G4H];   // prefetch, independent of h

        float2 accA0 = make_float2(q == 0 ? gval : 0.f, 0.f);
        float2 accA1 = make_float2(q == 1 ? gval : 0.f, 0.f);
        float2 accA2 = make_float2(q == 2 ? gval : 0.f, 0.f);
        float2 accA3 = make_float2(q == 3 ? gval : 0.f, 0.f);
        float2 accB0 = make_float2(0.f, 0.f);
        float2 accB1 = make_float2(0.f, 0.f);
        float2 accB2 = make_float2(0.f, 0.f);
        float2 accB3 = make_float2(0.f, 0.f);

        const float4* hb4 = (const float4*)&h_s[cur][q * 40];  // HPAD(q*32)=q*40

#define KK(kk4, Wg0, Wg1, Wg2, Wg3) { \
        float4 h4 = hb4[kk4]; \
        float2 hA = make_float2(h4.x, h4.y); \
        float2 hB = make_float2(h4.z, h4.w); \
        accA0 = pk_fma(hA, make_float2(Wg0.x, Wg0.y), accA0); \
        accB0 = pk_fma(hB, make_float2(Wg0.z, Wg0.w), accB0); \
        accA1 = pk_fma(hA, make_float2(Wg1.x, Wg1.y), accA1); \
        accB1 = pk_fma(hB, make_float2(Wg1.z, Wg1.w), accB1); \
        accA2 = pk_fma(hA, make_float2(Wg2.x, Wg2.y), accA2); \
        accB2 = pk_fma(hB, make_float2(Wg2.z, Wg2.w), accB2); \
        accA3 = pk_fma(hA, make_float2(Wg3.x, Wg3.y), accA3); \
        accB3 = pk_fma(hB, make_float2(Wg3.z, Wg3.w), accB3); }

        KK(0, W0,  W1,  W2,  W3)
        KK(1, W4,  W5,  W6,  W7)
        KK(2, W8,  W9,  W10, W11)
        KK(3, W12, W13, W14, W15)
        KK(4, W16, W17, W18, W19)
        KK(5, W20, W21, W22, W23)
        KK(6, W24, W25, W26, W27)
        KK(7, W28, W29, W30, W31)
#undef KK

        float a0 = quad_rsum(accA0.x + accA0.y + accB0.x + accB0.y);
        float a1 = quad_rsum(accA1.x + accA1.y + accB1.x + accB1.y);
        float a2 = quad_rsum(accA2.x + accA2.y + accB2.x + accB2.y);
        float a3 = quad_rsum(accA3.x + accA3.y + accB3.x + accB3.y);

        float iv = sigm_n(a0);
        float fv = sigm_n(a1);
        float gv = tanh_n(a2);
        float ov = sigm_n(a3);
        c = fv * c + iv * gv;
        float h = ov * tanh_n(c);

        if (q == 0) {
            h_s[cur ^ 1][HPAD(d)] = h;
            Hst[(size_t)t * Hsz] = h;
        }
        gval = ngval;
        __syncthreads();
        cur ^= 1;
    }
}

// ---------------- kernel 3a: scores + partial attn_c, grid (4 jt, 32 b) ----------------
__global__ __launch_bounds__(256) void scores_part(
    const float* __restrict__ H_all, const float* __restrict__ KV,
    const float* __restrict__ w1, const float* __restrict__ w2,
    float* __restrict__ attn_c) {
    const int b = blockIdx.y, jt = blockIdx.x;
    const int tid = threadIdx.x;
    __shared__ float hT[Hsz];
    __shared__ float q_s[Hsz];
    __shared__ float w2s[Hsz];
    __shared__ float s_s[64];
    __shared__ float part[2][Hsz];

    const float* Hb = H_all + (size_t)b * Tsz * Hsz;
    const float* KVb = KV + (size_t)b * Tsz * Hsz;

    if (tid < Hsz) {
        hT[tid] = Hb[255 * Hsz + tid];
        w2s[tid] = w2[tid];
    }
    __syncthreads();
    if (tid < Hsz) {
        float acc = 0.f;
        #pragma unroll 8
        for (int k = 0; k < Hsz; ++k) acc = fmaf(hT[k], w1[k * Hsz + tid], acc);
        q_s[tid] = acc;
    }
    __syncthreads();

    const int jl = tid >> 2, ql = tid & 3;
    const int j = jt * 64 + jl;
    float p = 0.f;
    if (j < 255) {
        const float* kv = KVb + (size_t)j * Hsz + ql * 32;
        const float* qs = q_s + ql * 32;
        const float* wv = w2s + ql * 32;
        #pragma unroll 8
        for (int k = 0; k < 32; ++k)
            p = fmaf(tanh_s(qs[k] + kv[k]), wv[k], p);
    }
    p = quad_rsum(p);
    if (ql == 0) s_s[jl] = (j < 255) ? p : 0.0f;
    __syncthreads();

    {
        const int dd = tid & 127, half = tid >> 7;
        float acc = 0.f;
        #pragma unroll 4
        for (int u = 0; u < 32; ++u) {
            int lj = half * 32 + u;
            int jj = jt * 64 + lj;
            if (jj < 255) acc = fmaf(s_s[lj], Hb[(size_t)jj * Hsz + dd], acc);
        }
        part[half][dd] = acc;
    }
    __syncthreads();
    if (tid < Hsz) atomicAdd(&attn_c[b * Hsz + tid], part[0][tid] + part[1][tid]);
}

// ---------------- kernel 3b: final FC ----------------
__global__ __launch_bounds__(256) void fc_out(
    const float* __restrict__ H_all, const float* __restrict__ attn_c,
    const float* __restrict__ w_fc, const float* __restrict__ b_fc,
    float* __restrict__ out) {
    const int b = blockIdx.x, tid = threadIdx.x;
    __shared__ float r_s[Hsz];
    if (tid < Hsz)
        r_s[tid] = H_all[(size_t)b * Tsz * Hsz + 255 * Hsz + tid] + attn_c[b * Hsz + tid];
    __syncthreads();
    const int o = tid >> 1, half = tid & 1;
    float acc = 0.f;
    if (o < Csz) {
        const float* wr = w_fc + (size_t)o * Hsz + half * 64;
        const float* rr = r_s + half * 64;
        #pragma unroll 8
        for (int k = 0; k < 64; ++k) acc = fmaf(rr[k], wr[k], acc);
    }
    acc += __shfl_xor(acc, 1);
    if (half == 0 && o < Csz) out[b * Csz + o] = acc + b_fc[o];
}

// ---------------- launch ----------------
extern "C" void kernel_launch(void* const* d_in, const int* in_sizes, int n_in,
                              void* d_out, int out_size, void* d_ws, size_t ws_size,
                              hipStream_t stream) {
    const float* x    = (const float*)d_in[0];
    const float* w_ih = (const float*)d_in[1];
    const float* b_ih = (const float*)d_in[2];
    const float* w_hh = (const float*)d_in[3];
    const float* b_hh = (const float*)d_in[4];
    const float* w1   = (const float*)d_in[5];
    const float* w2   = (const float*)d_in[6];
    const float* w_fc = (const float*)d_in[7];
    const float* b_fc = (const float*)d_in[8];

    float* ws = (float*)d_ws;
    float* whh_pk = ws;                               // 65536 f
    float* bias   = whh_pk + 65536;                   // 512 f
    float* attn_c = bias + 512;                       // 4096 f
    __hip_bfloat16* W2ih = (__hip_bfloat16*)(attn_c + 4096);         // 98304 f
    __hip_bfloat16* W2v  = (__hip_bfloat16*)(attn_c + 4096 + 98304); // 24576 f
    float* G      = attn_c + 4096 + 98304 + 24576;    // 8192*512 = 4194304 f
    float* H_all  = G + 4194304;                      // 1048576 f
    float* KV     = H_all + 1048576;                  // 1048576 f

    prep_kernel<<<256, 256, 0, stream>>>(w_ih, b_ih, w_hh, b_hh, w1,
                                         W2ih, W2v, whh_pk, bias, attn_c);

    dim3 gG(G4H / 64, (Bsz * Tsz) / 64);              // (8, 128)
    gemm_mfma_f32a<<<gG, 256, 0, stream>>>(x, W2ih, bias, G, Bsz * Tsz, G4H);

    lstm_seq<<<Bsz, 512, 0, stream>>>(G, whh_pk, H_all);

    dim3 gK(Hsz / 64, (Bsz * Tsz) / 64);              // (2, 128)
    gemm_mfma_f32a<<<gK, 256, 0, stream>>>(H_all, W2v, nullptr, KV, Bsz * Tsz, Hsz);

    dim3 gS(4, Bsz);                                  // (4 jt, 32 b)
    scores_part<<<gS, 256, 0, stream>>>(H_all, KV, w1, w2, attn_c);

    fc_out<<<Bsz, 256, 0, stream>>>(H_all, attn_c, w_fc, b_fc, (float*)d_out);
}